// Round 3
// baseline (1254.771 us; speedup 1.0000x reference)
//
#include <hip/hip_runtime.h>
#include <hip/hip_bf16.h>
#include <math.h>

#define NBLK 32          // 1024 rows / 32 rows-per-block
#define G 2              // independent row-groups per block (latency interleave)
#define NTHR 512
#define TPTS 96
#define CTOT 128
#define LDP 136          // LDS row pitch (u16): 128 + 8 pad -> 2-way banks (free)

typedef __bf16 bf16x8_t __attribute__((ext_vector_type(8)));
typedef float f32x4_t __attribute__((ext_vector_type(4)));
typedef unsigned short us8_t __attribute__((ext_vector_type(8)));

__device__ __forceinline__ unsigned short f2b(float f) {
    union { float f; unsigned int i; } v; v.f = f;
    unsigned int r = v.i + 0x7fffu + ((v.i >> 16) & 1u);
    return (unsigned short)(r >> 16);
}
__device__ __forceinline__ f32x4_t mfma16(bf16x8_t a, bf16x8_t b, f32x4_t c) {
    return __builtin_amdgcn_mfma_f32_16x16x32_bf16(a, b, c, 0, 0, 0);
}
// 8 consecutive bf16 (16B) from LDS or global
__device__ __forceinline__ bf16x8_t ldfrag(const unsigned short* p) {
    us8_t v = *(const us8_t*)p;
    return __builtin_bit_cast(bf16x8_t, v);
}
// 8 consecutive f32 from global -> bf16 fragment (RNE), 16B-aligned
__device__ __forceinline__ bf16x8_t ldfragW(const float* p) {
    float4 a = *(const float4*)p;
    float4 b = *(const float4*)(p + 4);
    bf16x8_t r;
    r[0] = __builtin_bit_cast(__bf16, f2b(a.x)); r[1] = __builtin_bit_cast(__bf16, f2b(a.y));
    r[2] = __builtin_bit_cast(__bf16, f2b(a.z)); r[3] = __builtin_bit_cast(__bf16, f2b(a.w));
    r[4] = __builtin_bit_cast(__bf16, f2b(b.x)); r[5] = __builtin_bit_cast(__bf16, f2b(b.y));
    r[6] = __builtin_bit_cast(__bf16, f2b(b.z)); r[7] = __builtin_bit_cast(__bf16, f2b(b.w));
    return r;
}
// pack 4 f32 -> 4 bf16, single 8B store
__device__ __forceinline__ void st_b64(unsigned short* d, float v0, float v1, float v2, float v3) {
    uint2 w;
    w.x = (unsigned int)f2b(v0) | ((unsigned int)f2b(v1) << 16);
    w.y = (unsigned int)f2b(v2) | ((unsigned int)f2b(v3) << 16);
    *(uint2*)d = w;
}
__device__ __forceinline__ float tanh_fast(float x) {
    float xc = fminf(fmaxf(x, -10.f), 10.f);
    float ez = __expf(-2.f * xc);
    return __fdividef(1.f - ez, 1.f + ez);
}
__device__ __forceinline__ float sigm(float x) {
    return __fdividef(1.f, 1.f + __expf(-x));
}

// Transposed formulation: all GEMMs computed as D = W * S  (D[out_feat][row]).
// MFMA C-layout: out_feat = wave*16 + quad*4 + i, row = lane&15  -> b64 LDS writes.
// Next-stage operand: S^T rows from LDS [row][feat] -> b128 reads (B-fragment).
// Per block: G=2 independent 16-row groups, interleaved to hide barrier/LDS latency.
__global__ void __launch_bounds__(NTHR, 2)
ode_forecaster(const float* __restrict__ yl,
               const float* __restrict__ yh,
               const float* __restrict__ Wode,
               const float* __restrict__ bode,
               const float* __restrict__ Wih0,
               const float* __restrict__ Whh0,
               const float* __restrict__ bih0,
               const float* __restrict__ bhh0,
               const float* __restrict__ Wih1,
               const float* __restrict__ Whh1,
               const float* __restrict__ bih1,
               const float* __restrict__ bhh1,
               const float* __restrict__ W1v,
               const float* __restrict__ b1v,
               const float* __restrict__ W2v,
               const float* __restrict__ b2v,
               float* __restrict__ outp,
               unsigned short* __restrict__ traj)
{
    const int tid   = threadIdx.x;
    const int lane  = tid & 63;
    const int wv    = tid >> 6;        // 0..7
    const int l15   = lane & 15;       // batch-row within group / A-row m
    const int quad  = lane >> 4;       // 0..3
    const int fbase = wv * 16 + quad * 4;  // this lane's 4 output feats (C-layout)
    const int rbase = blockIdx.x * (G * 16);

    __shared__ __align__(16) unsigned short zbuf[2][G][16][LDP];
    __shared__ __align__(16) unsigned short hidbuf[G][16][72];

    // traj layout: [t][1024 rows][128 feats] bf16
#define TRAJ(t, row) (traj + ((size_t)(t) * 1024 + (row)) * CTOT)

    // ---------------- ODE weights: A-frags W[m=l15][k] ------------------------
    bf16x8_t wode[4];
#pragma unroll
    for (int kt = 0; kt < 4; ++kt)
        wode[kt] = ldfragW(Wode + (wv * 16 + l15) * CTOT + kt * 32 + quad * 8);
    const float4 bo4 = *(const float4*)(bode + fbase);

    // ---------------- init y0 -------------------------------------------------
    float y[G][4];
#pragma unroll
    for (int g = 0; g < G; ++g) {
        int row = rbase + g * 16 + l15;
#pragma unroll
        for (int i = 0; i < 4; ++i) {
            int f = fbase + i;
            y[g][i] = (f < 32) ? yl[row * 32 + f] : yh[row * 96 + (f - 32)];
        }
        st_b64(&zbuf[0][g][l15][fbase], y[g][0], y[g][1], y[g][2], y[g][3]);
        st_b64(TRAJ(0, row) + fbase, y[g][0], y[g][1], y[g][2], y[g][3]);
    }
    __syncthreads();

    // ---------------- ODE: 95 dopri5 steps ------------------------------------
    const float dt = 1.0f / 95.0f;
    const float B1 = 35.f / 384.f, B3 = 500.f / 1113.f, B4 = 125.f / 192.f,
                B5 = -2187.f / 6784.f, B6 = 11.f / 84.f;

    int p = 0;
    float kr[G][6][4];
#pragma unroll 1
    for (int t = 0; t < 95; ++t) {
#pragma unroll
        for (int s = 0; s < 6; ++s) {
            f32x4_t acc[G];
#pragma unroll
            for (int g = 0; g < G; ++g) {
                bf16x8_t bf[4];
#pragma unroll
                for (int kt = 0; kt < 4; ++kt)
                    bf[kt] = ldfrag(&zbuf[p][g][l15][kt * 32 + quad * 8]);
                f32x4_t a = {0.f, 0.f, 0.f, 0.f};
#pragma unroll
                for (int kt = 0; kt < 4; ++kt) a = mfma16(wode[kt], bf[kt], a);
                acc[g] = a;
            }
#pragma unroll
            for (int g = 0; g < G; ++g) {
                kr[g][s][0] = tanh_fast(acc[g][0] + bo4.x);
                kr[g][s][1] = tanh_fast(acc[g][1] + bo4.y);
                kr[g][s][2] = tanh_fast(acc[g][2] + bo4.z);
                kr[g][s][3] = tanh_fast(acc[g][3] + bo4.w);
            }
#pragma unroll
            for (int g = 0; g < G; ++g) {
                float z[4];
                if (s < 5) {
#pragma unroll
                    for (int i = 0; i < 4; ++i) {
                        float zv;
                        if (s == 0)      zv = 0.2f * kr[g][0][i];
                        else if (s == 1) zv = (3.f/40.f)*kr[g][0][i] + (9.f/40.f)*kr[g][1][i];
                        else if (s == 2) zv = (44.f/45.f)*kr[g][0][i] + (-56.f/15.f)*kr[g][1][i] + (32.f/9.f)*kr[g][2][i];
                        else if (s == 3) zv = (19372.f/6561.f)*kr[g][0][i] + (-25360.f/2187.f)*kr[g][1][i]
                                            + (64448.f/6561.f)*kr[g][2][i] + (-212.f/729.f)*kr[g][3][i];
                        else             zv = (9017.f/3168.f)*kr[g][0][i] + (-355.f/33.f)*kr[g][1][i]
                                            + (46732.f/5247.f)*kr[g][2][i] + (49.f/176.f)*kr[g][3][i]
                                            + (-5103.f/18656.f)*kr[g][4][i];
                        z[i] = y[g][i] + dt * zv;
                    }
                    st_b64(&zbuf[p ^ 1][g][l15][fbase], z[0], z[1], z[2], z[3]);
                } else {
#pragma unroll
                    for (int i = 0; i < 4; ++i) {
                        float fc = B1*kr[g][0][i] + B3*kr[g][2][i] + B4*kr[g][3][i]
                                 + B5*kr[g][4][i] + B6*kr[g][5][i];
                        y[g][i] += dt * fc;
                    }
                    st_b64(&zbuf[p ^ 1][g][l15][fbase], y[g][0], y[g][1], y[g][2], y[g][3]);
                    int row = rbase + g * 16 + l15;
                    st_b64(TRAJ(t + 1, row) + fbase, y[g][0], y[g][1], y[g][2], y[g][3]);
                }
            }
            __syncthreads();
            p ^= 1;
        }
    }

    // ---------------- GRU layers ----------------------------------------------
    const float* WihL[2] = {Wih0, Wih1};
    const float* WhhL[2] = {Whh0, Whh1};
    const float* bihL[2] = {bih0, bih1};
    const float* bhhL[2] = {bhh0, bhh1};

    float h[G][4];
#pragma unroll 1
    for (int layer = 0; layer < 2; ++layer) {
        const float* Wih = WihL[layer];
        const float* Whh = WhhL[layer];
        // A-frags: gate-rows {g*128 + wv*16 + l15}, k = hidden feat
        bf16x8_t wih[3][4], whh[3][4];
#pragma unroll
        for (int gg = 0; gg < 3; ++gg) {
            int nrow = gg * 128 + wv * 16 + l15;
#pragma unroll
            for (int kt = 0; kt < 4; ++kt) {
                wih[gg][kt] = ldfragW(Wih + nrow * CTOT + kt * 32 + quad * 8);
                whh[gg][kt] = ldfragW(Whh + nrow * CTOT + kt * 32 + quad * 8);
            }
        }
        const float4 bir4 = *(const float4*)(bihL[layer] + 0 * 128 + fbase);
        const float4 biz4 = *(const float4*)(bihL[layer] + 1 * 128 + fbase);
        const float4 bin4 = *(const float4*)(bihL[layer] + 2 * 128 + fbase);
        const float4 bhr4 = *(const float4*)(bhhL[layer] + 0 * 128 + fbase);
        const float4 bhz4 = *(const float4*)(bhhL[layer] + 1 * 128 + fbase);
        const float4 bhn4 = *(const float4*)(bhhL[layer] + 2 * 128 + fbase);

#pragma unroll
        for (int g = 0; g < G; ++g) {
#pragma unroll
            for (int i = 0; i < 4; ++i) h[g][i] = 0.f;
            st_b64(&zbuf[0][g][l15][fbase], 0.f, 0.f, 0.f, 0.f);
        }
        p = 0;
        __syncthreads();

        // x B-frags for t=0 (prefetched pattern)
        bf16x8_t axc[G][4];
#pragma unroll
        for (int g = 0; g < G; ++g) {
            const unsigned short* xp = TRAJ(0, rbase + g * 16 + l15);
#pragma unroll
            for (int kt = 0; kt < 4; ++kt) axc[g][kt] = ldfrag(xp + kt * 32 + quad * 8);
        }

#pragma unroll 1
        for (int t = 0; t < TPTS; ++t) {
            // prefetch x_{t+1} BEFORE the traj write so loads aren't alias-stalled
            bf16x8_t axn[G][4];
            if (t + 1 < TPTS) {
#pragma unroll
                for (int g = 0; g < G; ++g) {
                    const unsigned short* xp = TRAJ(t + 1, rbase + g * 16 + l15);
#pragma unroll
                    for (int kt = 0; kt < 4; ++kt) axn[g][kt] = ldfrag(xp + kt * 32 + quad * 8);
                }
            }
            // delayed write of h1_{t-1} over traj[t-1] (consumed last iter)
            if (layer == 0 && t > 0) {
#pragma unroll
                for (int g = 0; g < G; ++g)
                    st_b64(TRAJ(t - 1, rbase + g * 16 + l15) + fbase,
                           h[g][0], h[g][1], h[g][2], h[g][3]);
            }
#pragma unroll
            for (int g = 0; g < G; ++g) {
                bf16x8_t ah[4];
#pragma unroll
                for (int kt = 0; kt < 4; ++kt)
                    ah[kt] = ldfrag(&zbuf[p][g][l15][kt * 32 + quad * 8]);
                f32x4_t air = {0,0,0,0}, aiz = {0,0,0,0}, ain = {0,0,0,0};
                f32x4_t ahr = {0,0,0,0}, ahz = {0,0,0,0}, ahn = {0,0,0,0};
#pragma unroll
                for (int kt = 0; kt < 4; ++kt) {
                    ahr = mfma16(whh[0][kt], ah[kt], ahr);
                    ahz = mfma16(whh[1][kt], ah[kt], ahz);
                    ahn = mfma16(whh[2][kt], ah[kt], ahn);
                    air = mfma16(wih[0][kt], axc[g][kt], air);
                    aiz = mfma16(wih[1][kt], axc[g][kt], aiz);
                    ain = mfma16(wih[2][kt], axc[g][kt], ain);
                }
                const float* birp = (const float*)&bir4;
                const float* bizp = (const float*)&biz4;
                const float* binp = (const float*)&bin4;
                const float* bhrp = (const float*)&bhr4;
                const float* bhzp = (const float*)&bhz4;
                const float* bhnp = (const float*)&bhn4;
#pragma unroll
                for (int i = 0; i < 4; ++i) {
                    float rr = sigm((air[i] + birp[i]) + (ahr[i] + bhrp[i]));
                    float zz = sigm((aiz[i] + bizp[i]) + (ahz[i] + bhzp[i]));
                    float nn = tanh_fast((ain[i] + binp[i]) + rr * (ahn[i] + bhnp[i]));
                    h[g][i] = (1.f - zz) * nn + zz * h[g][i];
                }
                st_b64(&zbuf[p ^ 1][g][l15][fbase], h[g][0], h[g][1], h[g][2], h[g][3]);
            }
            __syncthreads();
            p ^= 1;
            if (t + 1 < TPTS) {
#pragma unroll
                for (int g = 0; g < G; ++g)
#pragma unroll
                    for (int kt = 0; kt < 4; ++kt) axc[g][kt] = axn[g][kt];
            }
        }
        if (layer == 0) {
#pragma unroll
            for (int g = 0; g < G; ++g)
                st_b64(TRAJ(TPTS - 1, rbase + g * 16 + l15) + fbase,
                       h[g][0], h[g][1], h[g][2], h[g][3]);
        }
        // zbuf[p] holds bf16 of this layer's final h (layer1: h2)
    }

    // ---------------- MLP head ------------------------------------------------
    // hidden^T = gelu(W1 * h2^T): 4 m-tiles x G groups -> wave = (g<<2)|mt
    {
        int g  = wv >> 2;
        int mt = wv & 3;
        bf16x8_t bw[4], bh[4];
#pragma unroll
        for (int kt = 0; kt < 4; ++kt) {
            bw[kt] = ldfragW(W1v + (mt * 16 + l15) * CTOT + kt * 32 + quad * 8);
            bh[kt] = ldfrag(&zbuf[p][g][l15][kt * 32 + quad * 8]);
        }
        f32x4_t acc = {0.f, 0.f, 0.f, 0.f};
#pragma unroll
        for (int kt = 0; kt < 4; ++kt) acc = mfma16(bw[kt], bh[kt], acc);
        const float4 bb = *(const float4*)(b1v + mt * 16 + quad * 4);
        const float* bbp = (const float*)&bb;
        float gl[4];
#pragma unroll
        for (int i = 0; i < 4; ++i) {
            float x = acc[i] + bbp[i];
            gl[i] = 0.5f * x * (1.0f + erff(x * 0.70710678118654752f));
        }
        st_b64(&hidbuf[g][l15][mt * 16 + quad * 4], gl[0], gl[1], gl[2], gl[3]);
    }
    __syncthreads();

    // pred^T = W2 * hidden^T  [3072 x 16] per group; 24 m-tiles per wave
    bf16x8_t ahid[G][2];
#pragma unroll
    for (int g = 0; g < G; ++g)
#pragma unroll
        for (int kt = 0; kt < 2; ++kt)
            ahid[g][kt] = ldfrag(&hidbuf[g][l15][kt * 32 + quad * 8]);
#pragma unroll 1
    for (int j = 0; j < 24; ++j) {
        int mt2 = wv * 24 + j;            // output feat tile 0..191
        bf16x8_t wf0 = ldfragW(W2v + (mt2 * 16 + l15) * 64 + quad * 8);
        bf16x8_t wf1 = ldfragW(W2v + (mt2 * 16 + l15) * 64 + 32 + quad * 8);
        const float4 bv = *(const float4*)(b2v + mt2 * 16 + quad * 4);
        const float* bvp = (const float*)&bv;
#pragma unroll
        for (int g = 0; g < G; ++g) {
            f32x4_t acc = {0.f, 0.f, 0.f, 0.f};
            acc = mfma16(wf0, ahid[g][0], acc);
            acc = mfma16(wf1, ahid[g][1], acc);
            float4 o;
            o.x = acc[0] + bvp[0]; o.y = acc[1] + bvp[1];
            o.z = acc[2] + bvp[2]; o.w = acc[3] + bvp[3];
            *(float4*)(outp + (size_t)(rbase + g * 16 + l15) * 3072 + mt2 * 16 + quad * 4) = o;
        }
    }
#undef TRAJ
}

extern "C" void kernel_launch(void* const* d_in, const int* in_sizes, int n_in,
                              void* d_out, int out_size, void* d_ws, size_t ws_size,
                              hipStream_t stream) {
    // setup_inputs order: 0:x(unused) 1:yl 2:yh 3:W_ode 4:b_ode 5:W_ih0 6:W_hh0
    // 7:b_ih0 8:b_hh0 9:W_ih1 10:W_hh1 11:b_ih1 12:b_hh1 13:W1 14:b1 15:W2 16:b2
    const float* yl   = (const float*)d_in[1];
    const float* yh   = (const float*)d_in[2];
    const float* Wode = (const float*)d_in[3];
    const float* bode = (const float*)d_in[4];
    const float* Wih0 = (const float*)d_in[5];
    const float* Whh0 = (const float*)d_in[6];
    const float* bih0 = (const float*)d_in[7];
    const float* bhh0 = (const float*)d_in[8];
    const float* Wih1 = (const float*)d_in[9];
    const float* Whh1 = (const float*)d_in[10];
    const float* bih1 = (const float*)d_in[11];
    const float* bhh1 = (const float*)d_in[12];
    const float* W1v  = (const float*)d_in[13];
    const float* b1v  = (const float*)d_in[14];
    const float* W2v  = (const float*)d_in[15];
    const float* b2v  = (const float*)d_in[16];

    ode_forecaster<<<dim3(NBLK), dim3(NTHR), 0, stream>>>(
        yl, yh, Wode, bode, Wih0, Whh0, bih0, bhh0,
        Wih1, Whh1, bih1, bhh1, W1v, b1v, W2v, b2v,
        (float*)d_out, (unsigned short*)d_ws);
}

// Round 4
// 1095.084 us; speedup vs baseline: 1.1458x; 1.1458x over previous
//
#include <hip/hip_runtime.h>
#include <hip/hip_bf16.h>
#include <math.h>

#define NBLK 64          // 1024 rows / 16 rows-per-block
#define NTHR 256         // 4 waves; each wave owns feature tiles {wv, wv+4}
#define TT 2             // feature tiles per wave
#define TPTS 96
#define CTOT 128
#define LDP 134          // LDS row pitch u16 (67 dwords): reads/writes <=2-way banks

typedef __bf16 bf16x8_t __attribute__((ext_vector_type(8)));
typedef float f32x4_t __attribute__((ext_vector_type(4)));
typedef unsigned short us8_t __attribute__((ext_vector_type(8)));

__device__ __forceinline__ unsigned short f2b(float f) {
    union { float f; unsigned int i; } v; v.f = f;
    unsigned int r = v.i + 0x7fffu + ((v.i >> 16) & 1u);
    return (unsigned short)(r >> 16);
}
__device__ __forceinline__ f32x4_t mfma16(bf16x8_t a, bf16x8_t b, f32x4_t c) {
    return __builtin_amdgcn_mfma_f32_16x16x32_bf16(a, b, c, 0, 0, 0);
}
__device__ __forceinline__ bf16x8_t ldfrag(const unsigned short* p) {
    us8_t v = *(const us8_t*)p;
    return __builtin_bit_cast(bf16x8_t, v);
}
__device__ __forceinline__ bf16x8_t ldfragW(const float* p) {
    float4 a = *(const float4*)p;
    float4 b = *(const float4*)(p + 4);
    bf16x8_t r;
    r[0] = __builtin_bit_cast(__bf16, f2b(a.x)); r[1] = __builtin_bit_cast(__bf16, f2b(a.y));
    r[2] = __builtin_bit_cast(__bf16, f2b(a.z)); r[3] = __builtin_bit_cast(__bf16, f2b(a.w));
    r[4] = __builtin_bit_cast(__bf16, f2b(b.x)); r[5] = __builtin_bit_cast(__bf16, f2b(b.y));
    r[6] = __builtin_bit_cast(__bf16, f2b(b.z)); r[7] = __builtin_bit_cast(__bf16, f2b(b.w));
    return r;
}
__device__ __forceinline__ void st_b64(unsigned short* d, float v0, float v1, float v2, float v3) {
    uint2 w;
    w.x = (unsigned int)f2b(v0) | ((unsigned int)f2b(v1) << 16);
    w.y = (unsigned int)f2b(v2) | ((unsigned int)f2b(v3) << 16);
    *(uint2*)d = w;
}
__device__ __forceinline__ float tanh_fast(float x) {
    float xc = fminf(fmaxf(x, -10.f), 10.f);
    float ez = __expf(-2.f * xc);
    return __fdividef(1.f - ez, 1.f + ez);
}
__device__ __forceinline__ float sigm(float x) {
    return __fdividef(1.f, 1.f + __expf(-x));
}

// Transposed formulation (verified round 3): D = W * S^T, C-layout feat=quad*4+i,
// col=batch row=l15. 4 waves; wave wv owns feature tiles {wv, wv+4} and shares one
// set of B-operand LDS reads between them (halves LDS pipe pressure vs round 2).
__global__ void __launch_bounds__(NTHR, 1)
ode_forecaster(const float* __restrict__ yl,
               const float* __restrict__ yh,
               const float* __restrict__ Wode,
               const float* __restrict__ bode,
               const float* __restrict__ Wih0,
               const float* __restrict__ Whh0,
               const float* __restrict__ bih0,
               const float* __restrict__ bhh0,
               const float* __restrict__ Wih1,
               const float* __restrict__ Whh1,
               const float* __restrict__ bih1,
               const float* __restrict__ bhh1,
               const float* __restrict__ W1v,
               const float* __restrict__ b1v,
               const float* __restrict__ W2v,
               const float* __restrict__ b2v,
               float* __restrict__ outp,
               unsigned short* __restrict__ traj)
{
    const int tid   = threadIdx.x;
    const int lane  = tid & 63;
    const int wv    = tid >> 6;        // 0..3
    const int l15   = lane & 15;       // batch-row within block
    const int quad  = lane >> 4;       // 0..3
    const int rbase = blockIdx.x * 16;
    int fbase[TT];
#pragma unroll
    for (int tt = 0; tt < TT; ++tt) fbase[tt] = (wv + 4 * tt) * 16 + quad * 4;

    __shared__ __align__(16) unsigned short zbuf[2][16][LDP];
    __shared__ __align__(16) unsigned short hidbuf[16][72];

    // traj layout: [t][1024 rows][128 feats] bf16
#define TRAJ(t, row) (traj + ((size_t)(t) * 1024 + (row)) * CTOT)

    // ---------------- ODE weights: A-frags W[m][k], m = ftile*16 + l15 --------
    bf16x8_t wode[TT][4];
#pragma unroll
    for (int tt = 0; tt < TT; ++tt)
#pragma unroll
        for (int kt = 0; kt < 4; ++kt)
            wode[tt][kt] = ldfragW(Wode + ((wv + 4 * tt) * 16 + l15) * CTOT + kt * 32 + quad * 8);
    float bo[TT][4];
#pragma unroll
    for (int tt = 0; tt < TT; ++tt) {
        float4 b4 = *(const float4*)(bode + fbase[tt]);
        bo[tt][0] = b4.x; bo[tt][1] = b4.y; bo[tt][2] = b4.z; bo[tt][3] = b4.w;
    }

    // ---------------- init y0 -------------------------------------------------
    float y[TT][4];
    {
        int row = rbase + l15;
#pragma unroll
        for (int tt = 0; tt < TT; ++tt) {
#pragma unroll
            for (int i = 0; i < 4; ++i) {
                int f = fbase[tt] + i;
                y[tt][i] = (f < 32) ? yl[row * 32 + f] : yh[row * 96 + (f - 32)];
            }
            st_b64(&zbuf[0][l15][fbase[tt]], y[tt][0], y[tt][1], y[tt][2], y[tt][3]);
            st_b64(TRAJ(0, row) + fbase[tt], y[tt][0], y[tt][1], y[tt][2], y[tt][3]);
        }
    }
    __syncthreads();

    // ---------------- ODE: 95 dopri5 steps ------------------------------------
    const float dt = 1.0f / 95.0f;
    const float B1 = 35.f / 384.f, B3 = 500.f / 1113.f, B4 = 125.f / 192.f,
                B5 = -2187.f / 6784.f, B6 = 11.f / 84.f;

    int p = 0;
    float kr[TT][6][4];
#pragma unroll 1
    for (int t = 0; t < 95; ++t) {
#pragma unroll
        for (int s = 0; s < 6; ++s) {
            // one shared set of B-operand reads for both feature tiles
            bf16x8_t bf[4];
#pragma unroll
            for (int kt = 0; kt < 4; ++kt)
                bf[kt] = ldfrag(&zbuf[p][l15][kt * 32 + quad * 8]);
            f32x4_t acc[TT];
#pragma unroll
            for (int tt = 0; tt < TT; ++tt) {
                f32x4_t a = {0.f, 0.f, 0.f, 0.f};
#pragma unroll
                for (int kt = 0; kt < 4; ++kt) a = mfma16(wode[tt][kt], bf[kt], a);
                acc[tt] = a;
            }
#pragma unroll
            for (int tt = 0; tt < TT; ++tt)
#pragma unroll
                for (int i = 0; i < 4; ++i)
                    kr[tt][s][i] = tanh_fast(acc[tt][i] + bo[tt][i]);

#pragma unroll
            for (int tt = 0; tt < TT; ++tt) {
                if (s < 5) {
                    float z[4];
#pragma unroll
                    for (int i = 0; i < 4; ++i) {
                        float zv;
                        if (s == 0)      zv = 0.2f * kr[tt][0][i];
                        else if (s == 1) zv = (3.f/40.f)*kr[tt][0][i] + (9.f/40.f)*kr[tt][1][i];
                        else if (s == 2) zv = (44.f/45.f)*kr[tt][0][i] + (-56.f/15.f)*kr[tt][1][i] + (32.f/9.f)*kr[tt][2][i];
                        else if (s == 3) zv = (19372.f/6561.f)*kr[tt][0][i] + (-25360.f/2187.f)*kr[tt][1][i]
                                            + (64448.f/6561.f)*kr[tt][2][i] + (-212.f/729.f)*kr[tt][3][i];
                        else             zv = (9017.f/3168.f)*kr[tt][0][i] + (-355.f/33.f)*kr[tt][1][i]
                                            + (46732.f/5247.f)*kr[tt][2][i] + (49.f/176.f)*kr[tt][3][i]
                                            + (-5103.f/18656.f)*kr[tt][4][i];
                        z[i] = y[tt][i] + dt * zv;
                    }
                    st_b64(&zbuf[p ^ 1][l15][fbase[tt]], z[0], z[1], z[2], z[3]);
                } else {
#pragma unroll
                    for (int i = 0; i < 4; ++i) {
                        float fc = B1*kr[tt][0][i] + B3*kr[tt][2][i] + B4*kr[tt][3][i]
                                 + B5*kr[tt][4][i] + B6*kr[tt][5][i];
                        y[tt][i] += dt * fc;
                    }
                    st_b64(&zbuf[p ^ 1][l15][fbase[tt]], y[tt][0], y[tt][1], y[tt][2], y[tt][3]);
                    st_b64(TRAJ(t + 1, rbase + l15) + fbase[tt], y[tt][0], y[tt][1], y[tt][2], y[tt][3]);
                }
            }
            __syncthreads();
            p ^= 1;
        }
    }

    // ---------------- GRU layers ----------------------------------------------
    const float* WihL[2] = {Wih0, Wih1};
    const float* WhhL[2] = {Whh0, Whh1};
    const float* bihL[2] = {bih0, bih1};
    const float* bhhL[2] = {bhh0, bhh1};

    float h[TT][4];
#pragma unroll 1
    for (int layer = 0; layer < 2; ++layer) {
        const float* Wih = WihL[layer];
        const float* Whh = WhhL[layer];
        // A-frags for gate rows g*128 + ftile*16 + l15; [tt][gate][kt]
        bf16x8_t wih[TT][3][4], whh[TT][3][4];
#pragma unroll
        for (int tt = 0; tt < TT; ++tt)
#pragma unroll
            for (int gg = 0; gg < 3; ++gg) {
                int nrow = gg * 128 + (wv + 4 * tt) * 16 + l15;
#pragma unroll
                for (int kt = 0; kt < 4; ++kt) {
                    wih[tt][gg][kt] = ldfragW(Wih + nrow * CTOT + kt * 32 + quad * 8);
                    whh[tt][gg][kt] = ldfragW(Whh + nrow * CTOT + kt * 32 + quad * 8);
                }
            }
        float bi[TT][3][4], bh[TT][3][4];
#pragma unroll
        for (int tt = 0; tt < TT; ++tt)
#pragma unroll
            for (int gg = 0; gg < 3; ++gg) {
                float4 a = *(const float4*)(bihL[layer] + gg * 128 + fbase[tt]);
                float4 b = *(const float4*)(bhhL[layer] + gg * 128 + fbase[tt]);
                bi[tt][gg][0] = a.x; bi[tt][gg][1] = a.y; bi[tt][gg][2] = a.z; bi[tt][gg][3] = a.w;
                bh[tt][gg][0] = b.x; bh[tt][gg][1] = b.y; bh[tt][gg][2] = b.z; bh[tt][gg][3] = b.w;
            }

#pragma unroll
        for (int tt = 0; tt < TT; ++tt) {
#pragma unroll
            for (int i = 0; i < 4; ++i) h[tt][i] = 0.f;
            st_b64(&zbuf[0][l15][fbase[tt]], 0.f, 0.f, 0.f, 0.f);
        }
        p = 0;
        __syncthreads();

        // x B-frags for t=0
        bf16x8_t axc[4];
        {
            const unsigned short* xp = TRAJ(0, rbase + l15);
#pragma unroll
            for (int kt = 0; kt < 4; ++kt) axc[kt] = ldfrag(xp + kt * 32 + quad * 8);
        }

#pragma unroll 1
        for (int t = 0; t < TPTS; ++t) {
            // prefetch x_{t+1} before the (aliasing) delayed traj write
            bf16x8_t axn[4];
            if (t + 1 < TPTS) {
                const unsigned short* xp = TRAJ(t + 1, rbase + l15);
#pragma unroll
                for (int kt = 0; kt < 4; ++kt) axn[kt] = ldfrag(xp + kt * 32 + quad * 8);
            }
            // delayed write of h1_{t-1} over traj[t-1] (consumed last iter)
            if (layer == 0 && t > 0) {
#pragma unroll
                for (int tt = 0; tt < TT; ++tt)
                    st_b64(TRAJ(t - 1, rbase + l15) + fbase[tt],
                           h[tt][0], h[tt][1], h[tt][2], h[tt][3]);
            }
            bf16x8_t ah[4];
#pragma unroll
            for (int kt = 0; kt < 4; ++kt)
                ah[kt] = ldfrag(&zbuf[p][l15][kt * 32 + quad * 8]);

            f32x4_t gih[TT][3], ghh[TT][3];
#pragma unroll
            for (int tt = 0; tt < TT; ++tt)
#pragma unroll
                for (int gg = 0; gg < 3; ++gg) {
                    gih[tt][gg] = (f32x4_t){0.f, 0.f, 0.f, 0.f};
                    ghh[tt][gg] = (f32x4_t){0.f, 0.f, 0.f, 0.f};
                }
#pragma unroll
            for (int kt = 0; kt < 4; ++kt)
#pragma unroll
                for (int tt = 0; tt < TT; ++tt) {
                    ghh[tt][0] = mfma16(whh[tt][0][kt], ah[kt], ghh[tt][0]);
                    ghh[tt][1] = mfma16(whh[tt][1][kt], ah[kt], ghh[tt][1]);
                    ghh[tt][2] = mfma16(whh[tt][2][kt], ah[kt], ghh[tt][2]);
                    gih[tt][0] = mfma16(wih[tt][0][kt], axc[kt], gih[tt][0]);
                    gih[tt][1] = mfma16(wih[tt][1][kt], axc[kt], gih[tt][1]);
                    gih[tt][2] = mfma16(wih[tt][2][kt], axc[kt], gih[tt][2]);
                }
#pragma unroll
            for (int tt = 0; tt < TT; ++tt) {
#pragma unroll
                for (int i = 0; i < 4; ++i) {
                    float rr = sigm((gih[tt][0][i] + bi[tt][0][i]) + (ghh[tt][0][i] + bh[tt][0][i]));
                    float zz = sigm((gih[tt][1][i] + bi[tt][1][i]) + (ghh[tt][1][i] + bh[tt][1][i]));
                    float nn = tanh_fast((gih[tt][2][i] + bi[tt][2][i]) + rr * (ghh[tt][2][i] + bh[tt][2][i]));
                    h[tt][i] = (1.f - zz) * nn + zz * h[tt][i];
                }
                st_b64(&zbuf[p ^ 1][l15][fbase[tt]], h[tt][0], h[tt][1], h[tt][2], h[tt][3]);
            }
            __syncthreads();
            p ^= 1;
#pragma unroll
            for (int kt = 0; kt < 4; ++kt) axc[kt] = axn[kt];
        }
        if (layer == 0) {
#pragma unroll
            for (int tt = 0; tt < TT; ++tt)
                st_b64(TRAJ(TPTS - 1, rbase + l15) + fbase[tt],
                       h[tt][0], h[tt][1], h[tt][2], h[tt][3]);
        }
        // zbuf[p] holds bf16 of this layer's final h (layer1: h2)
    }

    // ---------------- MLP head ------------------------------------------------
    // hidden^T = gelu(W1 * h2^T): 4 m-tiles of 16 units, one per wave
    {
        bf16x8_t bw[4], bhh2[4];
#pragma unroll
        for (int kt = 0; kt < 4; ++kt) {
            bw[kt]   = ldfragW(W1v + (wv * 16 + l15) * CTOT + kt * 32 + quad * 8);
            bhh2[kt] = ldfrag(&zbuf[p][l15][kt * 32 + quad * 8]);
        }
        f32x4_t acc = {0.f, 0.f, 0.f, 0.f};
#pragma unroll
        for (int kt = 0; kt < 4; ++kt) acc = mfma16(bw[kt], bhh2[kt], acc);
        const float4 bb = *(const float4*)(b1v + wv * 16 + quad * 4);
        const float* bbp = (const float*)&bb;
        float gl[4];
#pragma unroll
        for (int i = 0; i < 4; ++i) {
            float x = acc[i] + bbp[i];
            gl[i] = 0.5f * x * (1.0f + erff(x * 0.70710678118654752f));
        }
        st_b64(&hidbuf[l15][wv * 16 + quad * 4], gl[0], gl[1], gl[2], gl[3]);
    }
    __syncthreads();

    // pred^T = W2 * hidden^T  [3072 x 16]; 48 m-tiles per wave
    bf16x8_t ahid[2];
#pragma unroll
    for (int kt = 0; kt < 2; ++kt)
        ahid[kt] = ldfrag(&hidbuf[l15][kt * 32 + quad * 8]);
#pragma unroll 1
    for (int j = 0; j < 48; ++j) {
        int mt2 = wv * 48 + j;            // output feat tile 0..191
        bf16x8_t wf0 = ldfragW(W2v + (mt2 * 16 + l15) * 64 + quad * 8);
        bf16x8_t wf1 = ldfragW(W2v + (mt2 * 16 + l15) * 64 + 32 + quad * 8);
        const float4 bv = *(const float4*)(b2v + mt2 * 16 + quad * 4);
        const float* bvp = (const float*)&bv;
        f32x4_t acc = {0.f, 0.f, 0.f, 0.f};
        acc = mfma16(wf0, ahid[0], acc);
        acc = mfma16(wf1, ahid[1], acc);
        float4 o;
        o.x = acc[0] + bvp[0]; o.y = acc[1] + bvp[1];
        o.z = acc[2] + bvp[2]; o.w = acc[3] + bvp[3];
        *(float4*)(outp + (size_t)(rbase + l15) * 3072 + mt2 * 16 + quad * 4) = o;
    }
#undef TRAJ
}

extern "C" void kernel_launch(void* const* d_in, const int* in_sizes, int n_in,
                              void* d_out, int out_size, void* d_ws, size_t ws_size,
                              hipStream_t stream) {
    // setup_inputs order: 0:x(unused) 1:yl 2:yh 3:W_ode 4:b_ode 5:W_ih0 6:W_hh0
    // 7:b_ih0 8:b_hh0 9:W_ih1 10:W_hh1 11:b_ih1 12:b_hh1 13:W1 14:b1 15:W2 16:b2
    const float* yl   = (const float*)d_in[1];
    const float* yh   = (const float*)d_in[2];
    const float* Wode = (const float*)d_in[3];
    const float* bode = (const float*)d_in[4];
    const float* Wih0 = (const float*)d_in[5];
    const float* Whh0 = (const float*)d_in[6];
    const float* bih0 = (const float*)d_in[7];
    const float* bhh0 = (const float*)d_in[8];
    const float* Wih1 = (const float*)d_in[9];
    const float* Whh1 = (const float*)d_in[10];
    const float* bih1 = (const float*)d_in[11];
    const float* bhh1 = (const float*)d_in[12];
    const float* W1v  = (const float*)d_in[13];
    const float* b1v  = (const float*)d_in[14];
    const float* W2v  = (const float*)d_in[15];
    const float* b2v  = (const float*)d_in[16];

    ode_forecaster<<<dim3(NBLK), dim3(NTHR), 0, stream>>>(
        yl, yh, Wode, bode, Wih0, Whh0, bih0, bhh0,
        Wih1, Whh1, bih1, bhh1, W1v, b1v, W2v, b2v,
        (float*)d_out, (unsigned short*)d_ws);
}